// Round 6
// baseline (3027.184 us; speedup 1.0000x reference)
//
#include <hip/hip_runtime.h>
#include <math.h>

#define T_STEPS 1024
#define I_DIM   128
#define H_DIM   512
#define O_DIM   512
#define M_PAT   32768
#define SCAN_ROLES 32   // single-wave WGs, one per CU of the elected XCD
#define VT_STR  32800   // padded key-stride of transposed V (breaks 64KB row aliasing)

typedef __attribute__((ext_vector_type(8))) short s16x8;
typedef __attribute__((ext_vector_type(4))) float f32x4;

__device__ __forceinline__ void bf_split(float f, unsigned short& hi, unsigned short& lo) {
  unsigned u = __builtin_bit_cast(unsigned, f);
  hi = (unsigned short)(u >> 16);                       // truncation split
  float r = f - __builtin_bit_cast(float, u & 0xFFFF0000u);
  lo = (unsigned short)(__builtin_bit_cast(unsigned, r) >> 16);
}
__device__ __forceinline__ unsigned short f2bf(float f) {
  return (unsigned short)(__builtin_bit_cast(unsigned, f) >> 16);
}
__device__ __forceinline__ float bf2f(unsigned short b) {
  return __builtin_bit_cast(float, ((unsigned)b) << 16);
}

// ---------------------------------------------------------------------------
// K0: xw[t][j] = inp[t,:] . W_ih[j,:] + b_ih[j] + b_hh[j]
// ---------------------------------------------------------------------------
__global__ __launch_bounds__(256) void xw_kernel(const float* __restrict__ inp,
    const float* __restrict__ W_ih, const float* __restrict__ b_ih,
    const float* __restrict__ b_hh, float* __restrict__ xw) {
  int t = blockIdx.x;
  __shared__ float4 xs4[I_DIM / 4];
  if (threadIdx.x < I_DIM / 4)
    xs4[threadIdx.x] = ((const float4*)(inp + (size_t)t * I_DIM))[threadIdx.x];
  __syncthreads();
  for (int j = threadIdx.x; j < H_DIM; j += 256) {
    const float4* w4 = (const float4*)(W_ih + (size_t)j * I_DIM);
    float acc = 0.f;
#pragma unroll
    for (int i = 0; i < I_DIM / 4; i++) {
      float4 w = w4[i]; float4 x = xs4[i];
      acc += w.x * x.x + w.y * x.y + w.z * x.z + w.w * x.w;
    }
    xw[(size_t)t * H_DIM + j] = acc + b_ih[j] + b_hh[j];
  }
}

// ---------------------------------------------------------------------------
// K1: RNN scan, self-signaling, 32 single-wave WGs (one per CU of elected XCD).
// Comms mechanism: agent-scope relaxed atomics on henc (verified rounds 1/3).
// Rounds 4/5 post-mortem: sc0-only inline-asm comms hung the container twice
// (suspect: sc0 scope on gfx950 may still L1-cache the poll line -> stale spin).
// Reverted; do NOT reintroduce without an on-device self-check.
// Round-5 structural findings applied here instead:
//  - vmcnt is FIFO: the per-step xw prefetch (LLC/HBM-latency load) was issued
//    BEFORE the poll loads, so every poll check's vmcnt wait also waited for
//    it -> ~500-900cyc added to the serial critical path EVERY step. Fix:
//    preload all xw[t][16 rows of this role] into a 64KB wave-private LDS
//    buffer before the t-loop; per-step xwv is a conflict-free ds_read.
//  - re-sweeps are now unconditional batched x8 relaxed loads (1 LLC RT per
//    sweep) instead of per-lane divergent conditional reloads.
// Signal encoding unchanged: enc = h+2.0 in [1,3]; poison/memset read <1.0.
// ---------------------------------------------------------------------------
__global__ __launch_bounds__(64, 1) void scan_kernel(
    const float* __restrict__ W_hh, const float* __restrict__ xw,
    const float* __restrict__ h0, float* __restrict__ g_cur,
    float* __restrict__ h_last, unsigned* __restrict__ sync,
    unsigned* __restrict__ henc) {
  unsigned* cnt  = sync + 64;      // [8] per-xcd registration
  unsigned* dec  = sync + 128;     // decision word (0 = undecided)
  __shared__ int role_s;
  if (threadIdx.x == 0) {
    unsigned xcd = __builtin_amdgcn_s_getreg(6164) & 7u;  // HW_REG_XCC_ID
    unsigned my_idx = __hip_atomic_fetch_add(&cnt[xcd], 1u, __ATOMIC_ACQ_REL,
                                             __HIP_MEMORY_SCOPE_AGENT);
    if (blockIdx.x == 0) {
      int chosen = -1;
      while (chosen < 0) {
        for (int x = 0; x < 8; x++)
          if (__hip_atomic_load(&cnt[x], __ATOMIC_ACQUIRE,
                                __HIP_MEMORY_SCOPE_AGENT) >= (unsigned)SCAN_ROLES) {
            chosen = x; break;
          }
        if (chosen < 0) __builtin_amdgcn_s_sleep(2);
      }
      __hip_atomic_store(dec, 1u + (unsigned)chosen, __ATOMIC_RELEASE,
                         __HIP_MEMORY_SCOPE_AGENT);
    }
    unsigned d;
    while ((d = __hip_atomic_load(dec, __ATOMIC_ACQUIRE,
                                  __HIP_MEMORY_SCOPE_AGENT)) == 0u)
      __builtin_amdgcn_s_sleep(2);
    role_s = (xcd == d - 1u && my_idx < (unsigned)SCAN_ROLES) ? (int)my_idx : -1;
  }
  __syncthreads();
  const int role = role_s;
  if (role < 0) return;

  const int lane = threadIdx.x;          // 0..63
  const int g    = lane & 3;             // col group: cols [g*128, g*128+128)
  const int row  = role * 16 + (lane >> 2);

  float4 w[32];
  const float4* wsrc = (const float4*)(W_hh + (size_t)row * H_DIM + g * 128);
#pragma unroll
  for (int i = 0; i < 32; i++) w[i] = wsrc[i];
#pragma unroll
  for (int i = 0; i < 32; i++) {
    asm volatile("" : "+v"(w[i].x), "+v"(w[i].y), "+v"(w[i].z), "+v"(w[i].w));
  }

  __shared__ float hbuf[528];            // 4 groups x 132 dwords (4-dword skew)
  __shared__ float xws[16384];           // 64KB: xw[t][16 rows of this role]

  // preload xw slice (one-time); keeps ALL xw traffic out of the poll's vmcnt
  {
    float4* dst4 = (float4*)xws;
    for (int i = lane; i < 4096; i += 64) {       // i = t*4 + q
      int tt = i >> 2, q = i & 3;
      dst4[i] = ((const float4*)(xw + (size_t)tt * H_DIM + role * 16))[q];
    }
  }

  for (int t = 0; t < T_STEPS; t++) {
    if (t == 0) {
#pragma unroll
      for (int j = 0; j < 8; j++) {
        int c = 64 * j + lane;
        hbuf[c + 4 * (j >> 1)] = h0[c];
      }
    } else {
      const unsigned* src = henc + (size_t)(t - 1) * H_DIM;
      unsigned u[8];
#pragma unroll
      for (int j = 0; j < 8; j++)
        u[j] = __hip_atomic_load(src + 64 * j + lane, __ATOMIC_RELAXED,
                                 __HIP_MEMORY_SCOPE_AGENT);
      for (;;) {
        bool ok = true;
#pragma unroll
        for (int j = 0; j < 8; j++)
          ok = ok && (__builtin_bit_cast(float, u[j]) >= 1.0f);
        if (ok) break;
#pragma unroll
        for (int j = 0; j < 8; j++)      // batched re-sweep: 1 RT, branch-free
          u[j] = __hip_atomic_load(src + 64 * j + lane, __ATOMIC_RELAXED,
                                   __HIP_MEMORY_SCOPE_AGENT);
      }
#pragma unroll
      for (int j = 0; j < 8; j++) {
        int c = 64 * j + lane;
        hbuf[c + 4 * (j >> 1)] = __builtin_bit_cast(float, u[j]) - 2.0f;
      }
    }
    // wave-private buffers: order stage/preload writes before reads (no barrier)
    asm volatile("s_waitcnt lgkmcnt(0)" ::: "memory");

    float xwv = xws[t * 16 + (lane >> 2)];

    const float4* hb = (const float4*)&hbuf[g * 132];
    float a0 = 0.f, a1 = 0.f, a2 = 0.f, a3 = 0.f;
#pragma unroll
    for (int i = 0; i < 8; i++) {
      float4 x0 = hb[4 * i], x1 = hb[4 * i + 1], x2 = hb[4 * i + 2], x3 = hb[4 * i + 3];
      float4 w0 = w[4 * i], w1 = w[4 * i + 1], w2 = w[4 * i + 2], w3 = w[4 * i + 3];
      a0 += x0.x * w0.x + x0.y * w0.y + x0.z * w0.z + x0.w * w0.w;
      a1 += x1.x * w1.x + x1.y * w1.y + x1.z * w1.z + x1.w * w1.w;
      a2 += x2.x * w2.x + x2.y * w2.y + x2.z * w2.z + x2.w * w2.w;
      a3 += x3.x * w3.x + x3.y * w3.y + x3.z * w3.z + x3.w * w3.w;
    }
    float a = (a0 + a1) + (a2 + a3);
    a += __shfl_xor(a, 1, 4);
    a += __shfl_xor(a, 2, 4);

    if (g == 0) {
      float pre = a + xwv;
      float e = __expf(2.f * pre);
      float h = 1.f - 2.f / (e + 1.f);
      // self-signaling store first (critical path), then plain output stores
      __hip_atomic_store(henc + (size_t)t * H_DIM + row,
                         __builtin_bit_cast(unsigned, h + 2.0f),
                         __ATOMIC_RELAXED, __HIP_MEMORY_SCOPE_AGENT);
      g_cur[(size_t)t * H_DIM + row] = h;
      if (t == T_STEPS - 1) h_last[row] = h;
    }
  }
}

// ---------------------------------------------------------------------------
// K2: key norms. bkx[m] = 8*||x_vals[m]||^2, bkg[m] = 8*||g_keys[m]||^2
// ---------------------------------------------------------------------------
__global__ __launch_bounds__(256) void norms_kernel(const float* __restrict__ patterns,
    float* __restrict__ bkx, float* __restrict__ bkg) {
  int lane = threadIdx.x & 63;
  int m = blockIdx.x * 4 + (threadIdx.x >> 6);
  const float4* row = (const float4*)(patterns + (size_t)m * (O_DIM + H_DIM));
  float ax = 0.f, ag = 0.f;
#pragma unroll
  for (int jj = 0; jj < 4; jj++) {
    float4 v = row[lane + 64 * jj];
    float s = v.x * v.x + v.y * v.y + v.z * v.z + v.w * v.w;
    if (jj < 2) ax += s; else ag += s;
  }
#pragma unroll
  for (int off = 1; off < 64; off <<= 1) {
    ax += __shfl_xor(ax, off, 64);
    ag += __shfl_xor(ag, off, 64);
  }
  if (lane == 0) { bkx[m] = 8.f * ax; bkg[m] = 8.f * ag; }
}

// ---------------------------------------------------------------------------
// K3: transpose x_vals -> Vt[vd][key] bf16 (trunc), padded stride VT_STR.
// ---------------------------------------------------------------------------
__global__ __launch_bounds__(256) void vt_kernel(const float* __restrict__ patterns,
                                                 unsigned short* __restrict__ Vt) {
  __shared__ unsigned short tile[64 * 68];
  int kt = blockIdx.x;   // key tile (64 keys)
  int vt = blockIdx.y;   // vd tile  (64 dims)
#pragma unroll
  for (int i = 0; i < 4; i++) {
    int f = threadIdx.x + 256 * i;        // 0..1023 : 64 keys x 16 float4
    int key = f >> 4, c4 = f & 15;
    float4 v = *(const float4*)(patterns + (size_t)(kt * 64 + key) * 1024 + vt * 64 + c4 * 4);
    unsigned short* dst = &tile[key * 68 + c4 * 4];
    dst[0] = f2bf(v.x); dst[1] = f2bf(v.y); dst[2] = f2bf(v.z); dst[3] = f2bf(v.w);
  }
  __syncthreads();
  int vd = threadIdx.x >> 2, q4 = threadIdx.x & 3;
  unsigned short tmp[16];
#pragma unroll
  for (int k = 0; k < 16; k++) tmp[k] = tile[(q4 * 16 + k) * 68 + vd];
  size_t ob = (size_t)(vt * 64 + vd) * VT_STR + kt * 64 + q4 * 16;
#pragma unroll
  for (int h = 0; h < 2; h++) {
    s16x8 pk;
#pragma unroll
    for (int j = 0; j < 8; j++) pk[j] = (short)tmp[h * 8 + j];
    *(s16x8*)&Vt[ob + h * 8] = pk;
  }
}

// ---------------------------------------------------------------------------
// K4: MFMA flash retrieval. logits = 16*(q.k) - 8*||k||^2, online softmax,
// split-bf16 QK (hi*hi + hi*lo + lo*hi), bf16 P & V for PV.
// ---------------------------------------------------------------------------
template <bool USE_VT>
__global__ __launch_bounds__(512, 2) void flash_kernel(
    const float* __restrict__ Qg, const float* __restrict__ Qx,
    const float* __restrict__ patterns, const float* __restrict__ bkx,
    const float* __restrict__ bkg, const unsigned short* __restrict__ Vt,
    float* __restrict__ pacc, float* __restrict__ pml, int S) {
  const int bid  = blockIdx.x;
  const int sidx = bid >> 6;            // key-split slow for L2 grouping
  const int ret  = (bid >> 5) & 1;
  const int qt   = bid & 31;
  const int qbase = qt * 32;

  const float* Qp  = ret ? Qx : Qg;
  const float* Kp  = patterns + (ret ? 0 : O_DIM);   // key cols
  const float* bkk = ret ? bkx : bkg;

  const int chunk = M_PAT / S;
  const int kbeg = sidx * chunk, kend = kbeg + chunk;

  const int lane = threadIdx.x & 63;
  const int wid  = threadIdx.x >> 6;    // 0..7
  const int qg   = wid >> 2;            // query group
  const int kw   = wid & 3;             // key sub-block / vd slice
  const int quad = lane >> 4;
  const int l16  = lane & 15;

  __shared__ unsigned short stage_u16[16384];       // 32 KB: khi / klo; aliases S_f
  __shared__ unsigned short p_lds[32 * 72];         // P bf16, padded stride 72
  __shared__ float mrow_s[32], lrow_s[32], alpha_s[32];
  __shared__ int flag_s;

  // ---- load Q fragments (A-layout: m=l16, k=quad*8+j), split hi/lo ----
  const int qrow = qbase + qg * 16 + l16;
  s16x8 qhi[16], qlo[16];
#pragma unroll
  for (int kst = 0; kst < 16; kst++) {
    const float4* src = (const float4*)(Qp + (size_t)qrow * 512 + kst * 32 + quad * 8);
    float4 a = src[0], b = src[1];
    float fv[8] = {a.x, a.y, a.z, a.w, b.x, b.y, b.z, b.w};
    s16x8 h, l;
#pragma unroll
    for (int j = 0; j < 8; j++) {
      unsigned short hb, lb; bf_split(fv[j], hb, lb);
      h[j] = (short)hb; l[j] = (short)lb;
    }
    qhi[kst] = h; qlo[kst] = l;
  }

  if (threadIdx.x < 32) { mrow_s[threadIdx.x] = -INFINITY; lrow_s[threadIdx.x] = 0.f; }

  f32x4 o[8];
#pragma unroll
  for (int nb = 0; nb < 8; nb++) o[nb] = (f32x4){0.f, 0.f, 0.f, 0.f};
  float ov[32];
  if (!USE_VT) {
#pragma unroll
    for (int j = 0; j < 32; j++) ov[j] = 0.f;
  }
  const int row2 = threadIdx.x >> 4;   // 0..31 (phase-2 / VALU-PV row)
  const int c0   = threadIdx.x & 15;

  for (int k0 = kbeg; k0 < kend; k0 += 64) {
    // ---------------- phase 1: scores ----------------
    f32x4 sc = (f32x4){0.f, 0.f, 0.f, 0.f};
#pragma unroll
    for (int dc = 0; dc < 4; dc++) {
      __syncthreads();                       // stage buffer free (prev reads done)
      if (dc == 0 && threadIdx.x == 0) flag_s = 0;
#pragma unroll
      for (int i = 0; i < 2; i++) {
        int oid = threadIdx.x + 512 * i;     // 1024 octets: key*16 + oct
        int key = oid >> 4, oct = oid & 15;
        const float4* src = (const float4*)(Kp + (size_t)(k0 + key) * 1024 + dc * 128 + oct * 8);
        float4 a = src[0], b = src[1];
        float fv[8] = {a.x, a.y, a.z, a.w, b.x, b.y, b.z, b.w};
        s16x8 hv, lv;
#pragma unroll
        for (int j = 0; j < 8; j++) {
          unsigned short hb, lb; bf_split(fv[j], hb, lb);
          hv[j] = (short)hb; lv[j] = (short)lb;
        }
        int base = (key * 16 + (oct ^ (key & 7))) * 8;
        *(s16x8*)&stage_u16[base] = hv;
        *(s16x8*)&stage_u16[8192 + base] = lv;
      }
      __syncthreads();
#pragma unroll
      for (int ks = 0; ks < 4; ks++) {
        int kst = dc * 4 + ks;
        int key = kw * 16 + l16;
        int oct = ks * 4 + quad;
        int base = (key * 16 + (oct ^ (key & 7))) * 8;
        s16x8 kh = *(const s16x8*)&stage_u16[base];
        s16x8 kl = *(const s16x8*)&stage_u16[8192 + base];
        sc = __builtin_amdgcn_mfma_f32_16x16x32_bf16(qhi[kst], kh, sc, 0, 0, 0);
        sc = __builtin_amdgcn_mfma_f32_16x16x32_bf16(qlo[kst], kh, sc, 0, 0, 0);
        sc = __builtin_amdgcn_mfma_f32_16x16x32_bf16(qhi[kst], kl, sc, 0, 0, 0);
      }
    }
    float bkv = bkk[k0 + kw * 16 + l16];
    __syncthreads();                         // all K reads done; stage aliases S_f now
    float* S_f = (float*)stage_u16;          // [32][68]
#pragma unroll
    for (int r = 0; r < 4; r++)
      S_f[(qg * 16 + quad * 4 + r) * 68 + kw * 16 + l16] = 16.f * sc[r] - bkv;
    __syncthreads();

    // ---------------- phase 2: online softmax ----------------
    float s4[4], p4[4];
#pragma unroll
    for (int c = 0; c < 4; c++) s4[c] = S_f[row2 * 68 + c0 + 16 * c];
    float tmax = fmaxf(fmaxf(s4[0], s4[1]), fmaxf(s4[2], s4[3]));
#pragma unroll
    for (int off = 1; off < 16; off <<= 1) tmax = fmaxf(tmax, __shfl_xor(tmax, off, 16));
    float mold = mrow_s[row2];
    float mnew = fmaxf(mold, tmax);
    float tsum = 0.f;
#pragma unroll
    for (int c = 0; c < 4; c++) { p4[c] = __expf(s4[c] - mnew); tsum += p4[c]; }
#pragma unroll
    for (int off = 1; off < 16; off <<= 1) tsum += __shfl_xor(tsum, off, 16);
#pragma unroll
    for (int c = 0; c < 4; c++) p_lds[row2 * 72 + c0 + 16 * c] = f2bf(p4[c]);
    if (c0 == 0) {
      float al = __expf(mold - mnew);
      alpha_s[row2] = al;
      mrow_s[row2] = mnew;
      lrow_s[row2] = lrow_s[row2] * al + tsum;
      if (tmax > mold - 25.f) flag_s = 1;
    }
    __syncthreads();
    const int doPV = flag_s;

    // ---------------- phase 3: PV ----------------
    if (doPV) {
      if (USE_VT) {
        float alr[4];
#pragma unroll
        for (int r = 0; r < 4; r++) alr[r] = alpha_s[qg * 16 + quad * 4 + r];
#pragma unroll
        for (int nb = 0; nb < 8; nb++) {
          o[nb][0] *= alr[0]; o[nb][1] *= alr[1]; o[nb][2] *= alr[2]; o[nb][3] *= alr[3];
        }
#pragma unroll
        for (int ks2 = 0; ks2 < 2; ks2++) {
          s16x8 pf = *(const s16x8*)&p_lds[(qg * 16 + l16) * 72 + ks2 * 32 + quad * 8];
#pragma unroll
          for (int nb = 0; nb < 8; nb++) {
            int vd = kw * 128 + nb * 16 + l16;
            s16x8 vf = *(const s16x8*)(Vt + (size_t)vd * VT_STR + (k0 + ks2 * 32 + quad * 8));
            o[nb] = __builtin_amdgcn_mfma_f32_16x16x32_bf16(pf, vf, o[nb], 0, 0, 0);
          }
        }
      } else {
        float al = alpha_s[row2];
#pragma unroll
        for (int j = 0; j < 32; j++) ov[j] *= al;
        for (int key = 0; key < 64; key++) {
          float w = bf2f(p_lds[row2 * 72 + key]);
          const float4* vsrc = (const float4*)(patterns + (size_t)(k0 + key) * 1024 + c0 * 32);
#pragma unroll
          for (int j = 0; j < 8; j++) {
            float4 v = vsrc[j];
            ov[4 * j + 0] += w * v.x; ov[4 * j + 1] += w * v.y;
            ov[4 * j + 2] += w * v.z; ov[4 * j + 3] += w * v.w;
          }
        }
      }
    }
  }

  // ---------------- epilogue: unnormalized partials + (m,l) ----------------
  __syncthreads();
  size_t pbase = ((size_t)(ret * S + sidx) * T_STEPS + qbase);
  if (USE_VT) {
#pragma unroll
    for (int nb = 0; nb < 8; nb++)
#pragma unroll
      for (int r = 0; r < 4; r++)
        pacc[(pbase + qg * 16 + quad * 4 + r) * 512 + kw * 128 + nb * 16 + l16] = o[nb][r];
  } else {
#pragma unroll
    for (int j = 0; j < 32; j++)
      pacc[(pbase + row2) * 512 + c0 * 32 + j] = ov[j];
  }
  if (threadIdx.x < 32) {
    pml[(pbase + threadIdx.x) * 2]     = mrow_s[threadIdx.x];
    pml[(pbase + threadIdx.x) * 2 + 1] = lrow_s[threadIdx.x];
  }
}

// ---------------------------------------------------------------------------
// K5: combine key-split partials -> prob_g / prob_x
// ---------------------------------------------------------------------------
__global__ __launch_bounds__(256) void combine_kernel(
    const float* __restrict__ pacc, const float* __restrict__ pml,
    float* __restrict__ out, int S) {
  int b = blockIdx.x;              // ret*1024 + r
  int ret = b >> 10, r = b & 1023;
  float M = -INFINITY;
  for (int s = 0; s < S; s++)
    M = fmaxf(M, pml[((size_t)(ret * S + s) * T_STEPS + r) * 2]);
  float L = 0.f;
  for (int s = 0; s < S; s++) {
    size_t mb = ((size_t)(ret * S + s) * T_STEPS + r) * 2;
    L += pml[mb + 1] * __expf(pml[mb] - M);
  }
  float inv = 1.0f / L;
  for (int cc = threadIdx.x; cc < 512; cc += 256) {
    float acc = 0.f;
    for (int s = 0; s < S; s++) {
      size_t mb = ((size_t)(ret * S + s) * T_STEPS + r) * 2;
      float sc = __expf(pml[mb] - M);
      acc += sc * pacc[((size_t)(ret * S + s) * T_STEPS + r) * 512 + cc];
    }
    out[(size_t)ret * (T_STEPS * O_DIM) + (size_t)r * 512 + cc] = acc * inv;
  }
}

// ---------------------------------------------------------------------------
extern "C" void kernel_launch(void* const* d_in, const int* in_sizes, int n_in,
                              void* d_out, int out_size, void* d_ws, size_t ws_size,
                              hipStream_t stream) {
  const float* inp      = (const float*)d_in[0];
  const float* x_obs    = (const float*)d_in[1];
  const float* patterns = (const float*)d_in[2];
  const float* h0       = (const float*)d_in[3];
  const float* W_ih     = (const float*)d_in[4];
  const float* W_hh     = (const float*)d_in[5];
  const float* b_ih     = (const float*)d_in[6];
  const float* b_hh     = (const float*)d_in[7];

  float* out    = (float*)d_out;
  float* g_cur  = out + 1048576;               // 1024*512
  float* h_last = out + 1572864;               // 512

  char* wsb = (char*)d_ws;
  size_t off = 0;
  auto alloc = [&](size_t bytes) -> char* {
    char* p = wsb + off; off += (bytes + 255) & ~(size_t)255; return p;
  };
  unsigned* sync = (unsigned*)alloc(8192);
  unsigned* henc = (unsigned*)alloc((size_t)T_STEPS * H_DIM * 4);   // 2 MB
  float* xw  = (float*)alloc((size_t)T_STEPS * H_DIM * 4);
  float* bkx = (float*)alloc((size_t)M_PAT * 4);
  float* bkg = (float*)alloc((size_t)M_PAT * 4);
  size_t base = off;

  const size_t vt_bytes = (size_t)512 * VT_STR * 2;
  auto pml_bytes  = [](int S) { return (size_t)2 * S * T_STEPS * 2 * 4; };
  auto pacc_bytes = [](int S) { return (size_t)2 * S * T_STEPS * 512 * 4; };

  int S = 4; bool use_vt = false;
  if (base + pml_bytes(4) + pacc_bytes(4) + vt_bytes + 1024 <= ws_size) { S = 4; use_vt = true; }
  else if (base + pml_bytes(2) + pacc_bytes(2) + vt_bytes + 1024 <= ws_size) { S = 2; use_vt = true; }
  else if (base + pml_bytes(4) + pacc_bytes(4) + 1024 <= ws_size) { S = 4; use_vt = false; }
  else if (base + pml_bytes(2) + pacc_bytes(2) + 1024 <= ws_size) { S = 2; use_vt = false; }
  else { S = 1; use_vt = false; }

  float* pml  = (float*)alloc(pml_bytes(S));
  float* pacc = (float*)alloc(pacc_bytes(S));
  unsigned short* Vt = use_vt ? (unsigned short*)alloc(vt_bytes) : (unsigned short*)nullptr;

  hipMemsetAsync(sync, 0, 8192, stream);
  hipMemsetAsync(henc, 0, (size_t)T_STEPS * H_DIM * 4, stream);
  xw_kernel<<<T_STEPS, 256, 0, stream>>>(inp, W_ih, b_ih, b_hh, xw);
  scan_kernel<<<1024, 64, 0, stream>>>(W_hh, xw, h0, g_cur, h_last, sync, henc);
  norms_kernel<<<M_PAT / 4, 256, 0, stream>>>(patterns, bkx, bkg);
  if (use_vt) {
    vt_kernel<<<dim3(512, 8), 256, 0, stream>>>(patterns, Vt);
    flash_kernel<true><<<S * 64, 512, 0, stream>>>(g_cur, x_obs, patterns, bkx, bkg,
                                                   Vt, pacc, pml, S);
  } else {
    flash_kernel<false><<<S * 64, 512, 0, stream>>>(g_cur, x_obs, patterns, bkx, bkg,
                                                    nullptr, pacc, pml, S);
  }
  combine_kernel<<<2 * T_STEPS, 256, 0, stream>>>(pacc, pml, out, S);
}

// Round 7
// 2647.622 us; speedup vs baseline: 1.1434x; 1.1434x over previous
//
#include <hip/hip_runtime.h>
#include <math.h>

#define T_STEPS 1024
#define I_DIM   128
#define H_DIM   512
#define O_DIM   512
#define M_PAT   32768
#define SCAN_ROLES 32   // single-wave WGs, one per CU of the elected XCD
#define VT_STR  32800   // padded key-stride of transposed V (breaks 64KB row aliasing)

typedef __attribute__((ext_vector_type(8))) short s16x8;
typedef __attribute__((ext_vector_type(4))) float f32x4;

__device__ __forceinline__ void bf_split(float f, unsigned short& hi, unsigned short& lo) {
  unsigned u = __builtin_bit_cast(unsigned, f);
  hi = (unsigned short)(u >> 16);                       // truncation split
  float r = f - __builtin_bit_cast(float, u & 0xFFFF0000u);
  lo = (unsigned short)(__builtin_bit_cast(unsigned, r) >> 16);
}
__device__ __forceinline__ unsigned short f2bf(float f) {
  return (unsigned short)(__builtin_bit_cast(unsigned, f) >> 16);
}
__device__ __forceinline__ float bf2f(unsigned short b) {
  return __builtin_bit_cast(float, ((unsigned)b) << 16);
}

// ---------------------------------------------------------------------------
// K0: xw[t][j] = inp[t,:] . W_ih[j,:] + b_ih[j] + b_hh[j]
// ---------------------------------------------------------------------------
__global__ __launch_bounds__(256) void xw_kernel(const float* __restrict__ inp,
    const float* __restrict__ W_ih, const float* __restrict__ b_ih,
    const float* __restrict__ b_hh, float* __restrict__ xw) {
  int t = blockIdx.x;
  __shared__ float4 xs4[I_DIM / 4];
  if (threadIdx.x < I_DIM / 4)
    xs4[threadIdx.x] = ((const float4*)(inp + (size_t)t * I_DIM))[threadIdx.x];
  __syncthreads();
  for (int j = threadIdx.x; j < H_DIM; j += 256) {
    const float4* w4 = (const float4*)(W_ih + (size_t)j * I_DIM);
    float acc = 0.f;
#pragma unroll
    for (int i = 0; i < I_DIM / 4; i++) {
      float4 w = w4[i]; float4 x = xs4[i];
      acc += w.x * x.x + w.y * x.y + w.z * x.z + w.w * x.w;
    }
    xw[(size_t)t * H_DIM + j] = acc + b_ih[j] + b_hh[j];
  }
}

// ---------------------------------------------------------------------------
// K1: RNN scan, self-signaling, 32 single-wave WGs (round-3 code, verified
// 1575us). ROUND-6 LESSON (do not re-litigate): VGPR=84 here means W_hh is
// NOT register-resident; the compiler reloads it from L2 each step, but those
// loads (and the xw_next prefetch) are poll-independent and hide inside the
// poll wait. Forcing them into LDS/registers (round 6: VGPR 132, 68KB LDS)
// REGRESSED 1575->1994us by disturbing that overlap. The per-step floor is
// the store->LLC->detect chain + max-over-32-producers jitter (the 8-word
// poll is a full 512-row barrier every step), not instruction placement.
// Rounds 4/5: sc0-only asm comms hung twice; agent-scope atomics only.
// Signal encoding: enc = h+2.0 in [1,3]; poison/memset read <1.0.
// ---------------------------------------------------------------------------
__global__ __launch_bounds__(64, 1) void scan_kernel(
    const float* __restrict__ W_hh, const float* __restrict__ xw,
    const float* __restrict__ h0, float* __restrict__ g_cur,
    float* __restrict__ h_last, unsigned* __restrict__ sync,
    unsigned* __restrict__ henc) {
  unsigned* cnt  = sync + 64;      // [8] per-xcd registration
  unsigned* dec  = sync + 128;     // decision word (0 = undecided)
  __shared__ int role_s;
  if (threadIdx.x == 0) {
    unsigned xcd = __builtin_amdgcn_s_getreg(6164) & 7u;  // HW_REG_XCC_ID
    unsigned my_idx = __hip_atomic_fetch_add(&cnt[xcd], 1u, __ATOMIC_ACQ_REL,
                                             __HIP_MEMORY_SCOPE_AGENT);
    if (blockIdx.x == 0) {
      int chosen = -1;
      while (chosen < 0) {
        for (int x = 0; x < 8; x++)
          if (__hip_atomic_load(&cnt[x], __ATOMIC_ACQUIRE,
                                __HIP_MEMORY_SCOPE_AGENT) >= (unsigned)SCAN_ROLES) {
            chosen = x; break;
          }
        if (chosen < 0) __builtin_amdgcn_s_sleep(2);
      }
      __hip_atomic_store(dec, 1u + (unsigned)chosen, __ATOMIC_RELEASE,
                         __HIP_MEMORY_SCOPE_AGENT);
    }
    unsigned d;
    while ((d = __hip_atomic_load(dec, __ATOMIC_ACQUIRE,
                                  __HIP_MEMORY_SCOPE_AGENT)) == 0u)
      __builtin_amdgcn_s_sleep(2);
    role_s = (xcd == d - 1u && my_idx < (unsigned)SCAN_ROLES) ? (int)my_idx : -1;
  }
  __syncthreads();
  const int role = role_s;
  if (role < 0) return;

  const int lane = threadIdx.x;          // 0..63
  const int g    = lane & 3;             // col group: cols [g*128, g*128+128)
  const int row  = role * 16 + (lane >> 2);

  float4 w[32];
  const float4* wsrc = (const float4*)(W_hh + (size_t)row * H_DIM + g * 128);
#pragma unroll
  for (int i = 0; i < 32; i++) w[i] = wsrc[i];
#pragma unroll
  for (int i = 0; i < 32; i++) {
    asm volatile("" : "+v"(w[i].x), "+v"(w[i].y), "+v"(w[i].z), "+v"(w[i].w));
  }

  __shared__ float hbuf[528];            // 4 groups x 132 dwords (4-dword skew)

  float xw_next = xw[row];               // xw[0*H + row]

  for (int t = 0; t < T_STEPS; t++) {
    float xwv = xw_next;
    if (t + 1 < T_STEPS)
      xw_next = xw[(size_t)(t + 1) * H_DIM + row];   // prefetch, hides in poll wait

    if (t == 0) {
#pragma unroll
      for (int j = 0; j < 8; j++) {
        int c = 64 * j + lane;
        hbuf[c + 4 * (j >> 1)] = h0[c];
      }
    } else {
      const unsigned* src = henc + (size_t)(t - 1) * H_DIM;
      unsigned u[8];
#pragma unroll
      for (int j = 0; j < 8; j++)
        u[j] = __hip_atomic_load(src + 64 * j + lane, __ATOMIC_RELAXED,
                                 __HIP_MEMORY_SCOPE_AGENT);
      bool again = true;
      while (again) {
        again = false;
#pragma unroll
        for (int j = 0; j < 8; j++)
          if (__builtin_bit_cast(float, u[j]) < 1.0f) {
            again = true;
            u[j] = __hip_atomic_load(src + 64 * j + lane, __ATOMIC_RELAXED,
                                     __HIP_MEMORY_SCOPE_AGENT);
          }
      }
#pragma unroll
      for (int j = 0; j < 8; j++) {
        int c = 64 * j + lane;
        hbuf[c + 4 * (j >> 1)] = __builtin_bit_cast(float, u[j]) - 2.0f;
      }
    }
    // wave-private buffer: order stage-writes before broadcast reads (no barrier)
    asm volatile("s_waitcnt lgkmcnt(0)" ::: "memory");

    const float4* hb = (const float4*)&hbuf[g * 132];
    float a0 = 0.f, a1 = 0.f, a2 = 0.f, a3 = 0.f;
#pragma unroll
    for (int i = 0; i < 8; i++) {
      float4 x0 = hb[4 * i], x1 = hb[4 * i + 1], x2 = hb[4 * i + 2], x3 = hb[4 * i + 3];
      float4 w0 = w[4 * i], w1 = w[4 * i + 1], w2 = w[4 * i + 2], w3 = w[4 * i + 3];
      a0 += x0.x * w0.x + x0.y * w0.y + x0.z * w0.z + x0.w * w0.w;
      a1 += x1.x * w1.x + x1.y * w1.y + x1.z * w1.z + x1.w * w1.w;
      a2 += x2.x * w2.x + x2.y * w2.y + x2.z * w2.z + x2.w * w2.w;
      a3 += x3.x * w3.x + x3.y * w3.y + x3.z * w3.z + x3.w * w3.w;
    }
    float a = (a0 + a1) + (a2 + a3);
    a += __shfl_xor(a, 1, 4);
    a += __shfl_xor(a, 2, 4);

    if (g == 0) {
      float pre = a + xwv;
      float e = __expf(2.f * pre);
      float h = 1.f - 2.f / (e + 1.f);
      // self-signaling store first (critical path), then plain output stores
      __hip_atomic_store(henc + (size_t)t * H_DIM + row,
                         __builtin_bit_cast(unsigned, h + 2.0f),
                         __ATOMIC_RELAXED, __HIP_MEMORY_SCOPE_AGENT);
      g_cur[(size_t)t * H_DIM + row] = h;
      if (t == T_STEPS - 1) h_last[row] = h;
    }
  }
}

// ---------------------------------------------------------------------------
// K2: key norms. bkx[m] = 8*||x_vals[m]||^2, bkg[m] = 8*||g_keys[m]||^2
// ---------------------------------------------------------------------------
__global__ __launch_bounds__(256) void norms_kernel(const float* __restrict__ patterns,
    float* __restrict__ bkx, float* __restrict__ bkg) {
  int lane = threadIdx.x & 63;
  int m = blockIdx.x * 4 + (threadIdx.x >> 6);
  const float4* row = (const float4*)(patterns + (size_t)m * (O_DIM + H_DIM));
  float ax = 0.f, ag = 0.f;
#pragma unroll
  for (int jj = 0; jj < 4; jj++) {
    float4 v = row[lane + 64 * jj];
    float s = v.x * v.x + v.y * v.y + v.z * v.z + v.w * v.w;
    if (jj < 2) ax += s; else ag += s;
  }
#pragma unroll
  for (int off = 1; off < 64; off <<= 1) {
    ax += __shfl_xor(ax, off, 64);
    ag += __shfl_xor(ag, off, 64);
  }
  if (lane == 0) { bkx[m] = 8.f * ax; bkg[m] = 8.f * ag; }
}

// ---------------------------------------------------------------------------
// K3: transpose x_vals -> Vt[vd][key] bf16 (trunc), padded stride VT_STR.
// ---------------------------------------------------------------------------
__global__ __launch_bounds__(256) void vt_kernel(const float* __restrict__ patterns,
                                                 unsigned short* __restrict__ Vt) {
  __shared__ unsigned short tile[64 * 68];
  int kt = blockIdx.x;   // key tile (64 keys)
  int vt = blockIdx.y;   // vd tile  (64 dims)
#pragma unroll
  for (int i = 0; i < 4; i++) {
    int f = threadIdx.x + 256 * i;        // 0..1023 : 64 keys x 16 float4
    int key = f >> 4, c4 = f & 15;
    float4 v = *(const float4*)(patterns + (size_t)(kt * 64 + key) * 1024 + vt * 64 + c4 * 4);
    unsigned short* dst = &tile[key * 68 + c4 * 4];
    dst[0] = f2bf(v.x); dst[1] = f2bf(v.y); dst[2] = f2bf(v.z); dst[3] = f2bf(v.w);
  }
  __syncthreads();
  int vd = threadIdx.x >> 2, q4 = threadIdx.x & 3;
  unsigned short tmp[16];
#pragma unroll
  for (int k = 0; k < 16; k++) tmp[k] = tile[(q4 * 16 + k) * 68 + vd];
  size_t ob = (size_t)(vt * 64 + vd) * VT_STR + kt * 64 + q4 * 16;
#pragma unroll
  for (int h = 0; h < 2; h++) {
    s16x8 pk;
#pragma unroll
    for (int j = 0; j < 8; j++) pk[j] = (short)tmp[h * 8 + j];
    *(s16x8*)&Vt[ob + h * 8] = pk;
  }
}

// ---------------------------------------------------------------------------
// K4: MFMA flash retrieval. logits = 16*(q.k) - 8*||k||^2, online softmax,
// split-bf16 QK (hi*hi + hi*lo + lo*hi), bf16 P & V for PV.
// Round-7: key-split raised to S=8 (512 blocks) so 2 blocks/CU co-reside
// (launch_bounds(512,2) capacity was half-used at S=4's 256 blocks); the
// 9-barriers-per-k0 structure idles a CU with only 1 resident block.
// ---------------------------------------------------------------------------
template <bool USE_VT>
__global__ __launch_bounds__(512, 2) void flash_kernel(
    const float* __restrict__ Qg, const float* __restrict__ Qx,
    const float* __restrict__ patterns, const float* __restrict__ bkx,
    const float* __restrict__ bkg, const unsigned short* __restrict__ Vt,
    float* __restrict__ pacc, float* __restrict__ pml, int S) {
  const int bid  = blockIdx.x;
  const int sidx = bid >> 6;            // key-split slow for L2 grouping
  const int ret  = (bid >> 5) & 1;
  const int qt   = bid & 31;
  const int qbase = qt * 32;

  const float* Qp  = ret ? Qx : Qg;
  const float* Kp  = patterns + (ret ? 0 : O_DIM);   // key cols
  const float* bkk = ret ? bkx : bkg;

  const int chunk = M_PAT / S;
  const int kbeg = sidx * chunk, kend = kbeg + chunk;

  const int lane = threadIdx.x & 63;
  const int wid  = threadIdx.x >> 6;    // 0..7
  const int qg   = wid >> 2;            // query group
  const int kw   = wid & 3;             // key sub-block / vd slice
  const int quad = lane >> 4;
  const int l16  = lane & 15;

  __shared__ unsigned short stage_u16[16384];       // 32 KB: khi / klo; aliases S_f
  __shared__ unsigned short p_lds[32 * 72];         // P bf16, padded stride 72
  __shared__ float mrow_s[32], lrow_s[32], alpha_s[32];
  __shared__ int flag_s;

  // ---- load Q fragments (A-layout: m=l16, k=quad*8+j), split hi/lo ----
  const int qrow = qbase + qg * 16 + l16;
  s16x8 qhi[16], qlo[16];
#pragma unroll
  for (int kst = 0; kst < 16; kst++) {
    const float4* src = (const float4*)(Qp + (size_t)qrow * 512 + kst * 32 + quad * 8);
    float4 a = src[0], b = src[1];
    float fv[8] = {a.x, a.y, a.z, a.w, b.x, b.y, b.z, b.w};
    s16x8 h, l;
#pragma unroll
    for (int j = 0; j < 8; j++) {
      unsigned short hb, lb; bf_split(fv[j], hb, lb);
      h[j] = (short)hb; l[j] = (short)lb;
    }
    qhi[kst] = h; qlo[kst] = l;
  }

  if (threadIdx.x < 32) { mrow_s[threadIdx.x] = -INFINITY; lrow_s[threadIdx.x] = 0.f; }

  f32x4 o[8];
#pragma unroll
  for (int nb = 0; nb < 8; nb++) o[nb] = (f32x4){0.f, 0.f, 0.f, 0.f};
  float ov[32];
  if (!USE_VT) {
#pragma unroll
    for (int j = 0; j < 32; j++) ov[j] = 0.f;
  }
  const int row2 = threadIdx.x >> 4;   // 0..31 (phase-2 / VALU-PV row)
  const int c0   = threadIdx.x & 15;

  for (int k0 = kbeg; k0 < kend; k0 += 64) {
    // ---------------- phase 1: scores ----------------
    f32x4 sc = (f32x4){0.f, 0.f, 0.f, 0.f};
#pragma unroll
    for (int dc = 0; dc < 4; dc++) {
      __syncthreads();                       // stage buffer free (prev reads done)
      if (dc == 0 && threadIdx.x == 0) flag_s = 0;
#pragma unroll
      for (int i = 0; i < 2; i++) {
        int oid = threadIdx.x + 512 * i;     // 1024 octets: key*16 + oct
        int key = oid >> 4, oct = oid & 15;
        const float4* src = (const float4*)(Kp + (size_t)(k0 + key) * 1024 + dc * 128 + oct * 8);
        float4 a = src[0], b = src[1];
        float fv[8] = {a.x, a.y, a.z, a.w, b.x, b.y, b.z, b.w};
        s16x8 hv, lv;
#pragma unroll
        for (int j = 0; j < 8; j++) {
          unsigned short hb, lb; bf_split(fv[j], hb, lb);
          hv[j] = (short)hb; lv[j] = (short)lb;
        }
        int base = (key * 16 + (oct ^ (key & 7))) * 8;
        *(s16x8*)&stage_u16[base] = hv;
        *(s16x8*)&stage_u16[8192 + base] = lv;
      }
      __syncthreads();
#pragma unroll
      for (int ks = 0; ks < 4; ks++) {
        int kst = dc * 4 + ks;
        int key = kw * 16 + l16;
        int oct = ks * 4 + quad;
        int base = (key * 16 + (oct ^ (key & 7))) * 8;
        s16x8 kh = *(const s16x8*)&stage_u16[base];
        s16x8 kl = *(const s16x8*)&stage_u16[8192 + base];
        sc = __builtin_amdgcn_mfma_f32_16x16x32_bf16(qhi[kst], kh, sc, 0, 0, 0);
        sc = __builtin_amdgcn_mfma_f32_16x16x32_bf16(qlo[kst], kh, sc, 0, 0, 0);
        sc = __builtin_amdgcn_mfma_f32_16x16x32_bf16(qhi[kst], kl, sc, 0, 0, 0);
      }
    }
    float bkv = bkk[k0 + kw * 16 + l16];
    __syncthreads();                         // all K reads done; stage aliases S_f now
    float* S_f = (float*)stage_u16;          // [32][68]
#pragma unroll
    for (int r = 0; r < 4; r++)
      S_f[(qg * 16 + quad * 4 + r) * 68 + kw * 16 + l16] = 16.f * sc[r] - bkv;
    __syncthreads();

    // ---------------- phase 2: online softmax ----------------
    float s4[4], p4[4];
#pragma unroll
    for (int c = 0; c < 4; c++) s4[c] = S_f[row2 * 68 + c0 + 16 * c];
    float tmax = fmaxf(fmaxf(s4[0], s4[1]), fmaxf(s4[2], s4[3]));
#pragma unroll
    for (int off = 1; off < 16; off <<= 1) tmax = fmaxf(tmax, __shfl_xor(tmax, off, 16));
    float mold = mrow_s[row2];
    float mnew = fmaxf(mold, tmax);
    float tsum = 0.f;
#pragma unroll
    for (int c = 0; c < 4; c++) { p4[c] = __expf(s4[c] - mnew); tsum += p4[c]; }
#pragma unroll
    for (int off = 1; off < 16; off <<= 1) tsum += __shfl_xor(tsum, off, 16);
#pragma unroll
    for (int c = 0; c < 4; c++) p_lds[row2 * 72 + c0 + 16 * c] = f2bf(p4[c]);
    if (c0 == 0) {
      float al = __expf(mold - mnew);
      alpha_s[row2] = al;
      mrow_s[row2] = mnew;
      lrow_s[row2] = lrow_s[row2] * al + tsum;
      if (tmax > mold - 25.f) flag_s = 1;
    }
    __syncthreads();
    const int doPV = flag_s;

    // ---------------- phase 3: PV ----------------
    if (doPV) {
      if (USE_VT) {
        float alr[4];
#pragma unroll
        for (int r = 0; r < 4; r++) alr[r] = alpha_s[qg * 16 + quad * 4 + r];
#pragma unroll
        for (int nb = 0; nb < 8; nb++) {
          o[nb][0] *= alr[0]; o[nb][1] *= alr[1]; o[nb][2] *= alr[2]; o[nb][3] *= alr[3];
        }
#pragma unroll
        for (int ks2 = 0; ks2 < 2; ks2++) {
          s16x8 pf = *(const s16x8*)&p_lds[(qg * 16 + l16) * 72 + ks2 * 32 + quad * 8];
#pragma unroll
          for (int nb = 0; nb < 8; nb++) {
            int vd = kw * 128 + nb * 16 + l16;
            s16x8 vf = *(const s16x8*)(Vt + (size_t)vd * VT_STR + (k0 + ks2 * 32 + quad * 8));
            o[nb] = __builtin_amdgcn_mfma_f32_16x16x32_bf16(pf, vf, o[nb], 0, 0, 0);
          }
        }
      } else {
        float al = alpha_s[row2];
#pragma unroll
        for (int j = 0; j < 32; j++) ov[j] *= al;
        for (int key = 0; key < 64; key++) {
          float w = bf2f(p_lds[row2 * 72 + key]);
          const float4* vsrc = (const float4*)(patterns + (size_t)(k0 + key) * 1024 + c0 * 32);
#pragma unroll
          for (int j = 0; j < 8; j++) {
            float4 v = vsrc[j];
            ov[4 * j + 0] += w * v.x; ov[4 * j + 1] += w * v.y;
            ov[4 * j + 2] += w * v.z; ov[4 * j + 3] += w * v.w;
          }
        }
      }
    }
  }

  // ---------------- epilogue: unnormalized partials + (m,l) ----------------
  __syncthreads();
  size_t pbase = ((size_t)(ret * S + sidx) * T_STEPS + qbase);
  if (USE_VT) {
#pragma unroll
    for (int nb = 0; nb < 8; nb++)
#pragma unroll
      for (int r = 0; r < 4; r++)
        pacc[(pbase + qg * 16 + quad * 4 + r) * 512 + kw * 128 + nb * 16 + l16] = o[nb][r];
  } else {
#pragma unroll
    for (int j = 0; j < 32; j++)
      pacc[(pbase + row2) * 512 + c0 * 32 + j] = ov[j];
  }
  if (threadIdx.x < 32) {
    pml[(pbase + threadIdx.x) * 2]     = mrow_s[threadIdx.x];
    pml[(pbase + threadIdx.x) * 2 + 1] = lrow_s[threadIdx.x];
  }
}

// ---------------------------------------------------------------------------
// K5: combine key-split partials -> prob_g / prob_x
// ---------------------------------------------------------------------------
__global__ __launch_bounds__(256) void combine_kernel(
    const float* __restrict__ pacc, const float* __restrict__ pml,
    float* __restrict__ out, int S) {
  int b = blockIdx.x;              // ret*1024 + r
  int ret = b >> 10, r = b & 1023;
  float M = -INFINITY;
  for (int s = 0; s < S; s++)
    M = fmaxf(M, pml[((size_t)(ret * S + s) * T_STEPS + r) * 2]);
  float L = 0.f;
  for (int s = 0; s < S; s++) {
    size_t mb = ((size_t)(ret * S + s) * T_STEPS + r) * 2;
    L += pml[mb + 1] * __expf(pml[mb] - M);
  }
  float inv = 1.0f / L;
  for (int cc = threadIdx.x; cc < 512; cc += 256) {
    float acc = 0.f;
    for (int s = 0; s < S; s++) {
      size_t mb = ((size_t)(ret * S + s) * T_STEPS + r) * 2;
      float sc = __expf(pml[mb] - M);
      acc += sc * pacc[((size_t)(ret * S + s) * T_STEPS + r) * 512 + cc];
    }
    out[(size_t)ret * (T_STEPS * O_DIM) + (size_t)r * 512 + cc] = acc * inv;
  }
}

// ---------------------------------------------------------------------------
extern "C" void kernel_launch(void* const* d_in, const int* in_sizes, int n_in,
                              void* d_out, int out_size, void* d_ws, size_t ws_size,
                              hipStream_t stream) {
  const float* inp      = (const float*)d_in[0];
  const float* x_obs    = (const float*)d_in[1];
  const float* patterns = (const float*)d_in[2];
  const float* h0       = (const float*)d_in[3];
  const float* W_ih     = (const float*)d_in[4];
  const float* W_hh     = (const float*)d_in[5];
  const float* b_ih     = (const float*)d_in[6];
  const float* b_hh     = (const float*)d_in[7];

  float* out    = (float*)d_out;
  float* g_cur  = out + 1048576;               // 1024*512
  float* h_last = out + 1572864;               // 512

  char* wsb = (char*)d_ws;
  size_t off = 0;
  auto alloc = [&](size_t bytes) -> char* {
    char* p = wsb + off; off += (bytes + 255) & ~(size_t)255; return p;
  };
  unsigned* sync = (unsigned*)alloc(8192);
  unsigned* henc = (unsigned*)alloc((size_t)T_STEPS * H_DIM * 4);   // 2 MB
  float* xw  = (float*)alloc((size_t)T_STEPS * H_DIM * 4);
  float* bkx = (float*)alloc((size_t)M_PAT * 4);
  float* bkg = (float*)alloc((size_t)M_PAT * 4);
  size_t base = off;

  const size_t vt_bytes = (size_t)512 * VT_STR * 2;
  auto pml_bytes  = [](int S) { return (size_t)2 * S * T_STEPS * 2 * 4; };
  auto pacc_bytes = [](int S) { return (size_t)2 * S * T_STEPS * 512 * 4; };

  int S = 4; bool use_vt = false;
  if (base + pml_bytes(8) + pacc_bytes(8) + vt_bytes + 1024 <= ws_size) { S = 8; use_vt = true; }
  else if (base + pml_bytes(4) + pacc_bytes(4) + vt_bytes + 1024 <= ws_size) { S = 4; use_vt = true; }
  else if (base + pml_bytes(2) + pacc_bytes(2) + vt_bytes + 1024 <= ws_size) { S = 2; use_vt = true; }
  else if (base + pml_bytes(4) + pacc_bytes(4) + 1024 <= ws_size) { S = 4; use_vt = false; }
  else if (base + pml_bytes(2) + pacc_bytes(2) + 1024 <= ws_size) { S = 2; use_vt = false; }
  else { S = 1; use_vt = false; }

  float* pml  = (float*)alloc(pml_bytes(S));
  float* pacc = (float*)alloc(pacc_bytes(S));
  unsigned short* Vt = use_vt ? (unsigned short*)alloc(vt_bytes) : (unsigned short*)nullptr;

  hipMemsetAsync(sync, 0, 8192, stream);
  hipMemsetAsync(henc, 0, (size_t)T_STEPS * H_DIM * 4, stream);
  xw_kernel<<<T_STEPS, 256, 0, stream>>>(inp, W_ih, b_ih, b_hh, xw);
  scan_kernel<<<1024, 64, 0, stream>>>(W_hh, xw, h0, g_cur, h_last, sync, henc);
  norms_kernel<<<M_PAT / 4, 256, 0, stream>>>(patterns, bkx, bkg);
  if (use_vt) {
    vt_kernel<<<dim3(512, 8), 256, 0, stream>>>(patterns, Vt);
    flash_kernel<true><<<S * 64, 512, 0, stream>>>(g_cur, x_obs, patterns, bkx, bkg,
                                                   Vt, pacc, pml, S);
  } else {
    flash_kernel<false><<<S * 64, 512, 0, stream>>>(g_cur, x_obs, patterns, bkx, bkg,
                                                    nullptr, pacc, pml, S);
  }
  combine_kernel<<<2 * T_STEPS, 256, 0, stream>>>(pacc, pml, out, S);
}

// Round 8
// 2180.559 us; speedup vs baseline: 1.3883x; 1.2142x over previous
//
#include <hip/hip_runtime.h>
#include <math.h>

#define T_STEPS 1024
#define I_DIM   128
#define H_DIM   512
#define O_DIM   512
#define M_PAT   32768
#define SCAN_ROLES 32   // scan blocks on the elected XCD
#define VT_STR  32800   // padded key-stride of transposed V (breaks 64KB row aliasing)

typedef __attribute__((ext_vector_type(8))) short s16x8;
typedef __attribute__((ext_vector_type(4))) float f32x4;

__device__ __forceinline__ void bf_split(float f, unsigned short& hi, unsigned short& lo) {
  unsigned u = __builtin_bit_cast(unsigned, f);
  hi = (unsigned short)(u >> 16);                       // truncation split
  float r = f - __builtin_bit_cast(float, u & 0xFFFF0000u);
  lo = (unsigned short)(__builtin_bit_cast(unsigned, r) >> 16);
}
__device__ __forceinline__ unsigned short f2bf(float f) {
  return (unsigned short)(__builtin_bit_cast(unsigned, f) >> 16);
}
__device__ __forceinline__ float bf2f(unsigned short b) {
  return __builtin_bit_cast(float, ((unsigned)b) << 16);
}

// ---------------------------------------------------------------------------
// K0: xw[t][j] = inp[t,:] . W_ih[j,:] + b_ih[j] + b_hh[j]
// ---------------------------------------------------------------------------
__global__ __launch_bounds__(256) void xw_kernel(const float* __restrict__ inp,
    const float* __restrict__ W_ih, const float* __restrict__ b_ih,
    const float* __restrict__ b_hh, float* __restrict__ xw) {
  int t = blockIdx.x;
  __shared__ float4 xs4[I_DIM / 4];
  if (threadIdx.x < I_DIM / 4)
    xs4[threadIdx.x] = ((const float4*)(inp + (size_t)t * I_DIM))[threadIdx.x];
  __syncthreads();
  for (int j = threadIdx.x; j < H_DIM; j += 256) {
    const float4* w4 = (const float4*)(W_ih + (size_t)j * I_DIM);
    float acc = 0.f;
#pragma unroll
    for (int i = 0; i < I_DIM / 4; i++) {
      float4 w = w4[i]; float4 x = xs4[i];
      acc += w.x * x.x + w.y * x.y + w.z * x.z + w.w * x.w;
    }
    xw[(size_t)t * H_DIM + j] = acc + b_ih[j] + b_hh[j];
  }
}

// ---------------------------------------------------------------------------
// K2: key norms. bkx[m] = 8*||x_vals[m]||^2, bkg[m] = 8*||g_keys[m]||^2
// ---------------------------------------------------------------------------
__global__ __launch_bounds__(256) void norms_kernel(const float* __restrict__ patterns,
    float* __restrict__ bkx, float* __restrict__ bkg) {
  int lane = threadIdx.x & 63;
  int m = blockIdx.x * 4 + (threadIdx.x >> 6);
  const float4* row = (const float4*)(patterns + (size_t)m * (O_DIM + H_DIM));
  float ax = 0.f, ag = 0.f;
#pragma unroll
  for (int jj = 0; jj < 4; jj++) {
    float4 v = row[lane + 64 * jj];
    float s = v.x * v.x + v.y * v.y + v.z * v.z + v.w * v.w;
    if (jj < 2) ax += s; else ag += s;
  }
#pragma unroll
  for (int off = 1; off < 64; off <<= 1) {
    ax += __shfl_xor(ax, off, 64);
    ag += __shfl_xor(ag, off, 64);
  }
  if (lane == 0) { bkx[m] = 8.f * ax; bkg[m] = 8.f * ag; }
}

// ---------------------------------------------------------------------------
// K3: transpose x_vals -> Vt[vd][key] bf16 (trunc), padded stride VT_STR.
// ---------------------------------------------------------------------------
__global__ __launch_bounds__(256) void vt_kernel(const float* __restrict__ patterns,
                                                 unsigned short* __restrict__ Vt) {
  __shared__ unsigned short tile[64 * 68];
  int kt = blockIdx.x;   // key tile (64 keys)
  int vt = blockIdx.y;   // vd tile  (64 dims)
#pragma unroll
  for (int i = 0; i < 4; i++) {
    int f = threadIdx.x + 256 * i;        // 0..1023 : 64 keys x 16 float4
    int key = f >> 4, c4 = f & 15;
    float4 v = *(const float4*)(patterns + (size_t)(kt * 64 + key) * 1024 + vt * 64 + c4 * 4);
    unsigned short* dst = &tile[key * 68 + c4 * 4];
    dst[0] = f2bf(v.x); dst[1] = f2bf(v.y); dst[2] = f2bf(v.z); dst[3] = f2bf(v.w);
  }
  __syncthreads();
  int vd = threadIdx.x >> 2, q4 = threadIdx.x & 3;
  unsigned short tmp[16];
#pragma unroll
  for (int k = 0; k < 16; k++) tmp[k] = tile[(q4 * 16 + k) * 68 + vd];
  size_t ob = (size_t)(vt * 64 + vd) * VT_STR + kt * 64 + q4 * 16;
#pragma unroll
  for (int h = 0; h < 2; h++) {
    s16x8 pk;
#pragma unroll
    for (int j = 0; j < 8; j++) pk[j] = (short)tmp[h * 8 + j];
    *(s16x8*)&Vt[ob + h * 8] = pk;
  }
}

// ---------------------------------------------------------------------------
// FUSED: scan (round-3 body, verified 1575us) + flash retrieval helpers.
// Round-8 rationale: scan occupies only the elected XCD; during its 1575us,
// 224 CUs were idle while ~900us of flash ran AFTER it serially. Fusion:
//  - 1024 blocks x 512 threads. Election as before (block-granular).
//  - Elected-XCD blocks: my_idx<32 -> wave 0 runs scan (waves 1-7 exit after
//    the one all-waves barrier; scan t-loop is barrier-free). my_idx>=32 ->
//    exit (keeps scan XCD as clean as the standalone launch; round-6 lesson).
//  - All other blocks: pop flash units (ret,qt,sidx) from a global atomic.
//    Order: all ret=1 (x-retrieval, no scan dependency) first, then ret=0
//    ascending qt. ret=0 reads Q directly from henc (value-encoded h+2.0,
//    relaxed agent loads, s_sleep back-off) -> prob_g streams BEHIND the
//    scan frontier (q-tile qt ready at ~(qt+1)*49us, not 1575us).
//  - Scan never waits on helpers -> no circular dependency. Helpers' henc
//    spins terminate because scan progress is helper-independent.
// Signal encoding: enc = h+2.0 in [1,3]; poison/memset read <1.0.
// ---------------------------------------------------------------------------
template <bool USE_VT>
__global__ __launch_bounds__(512, 2) void fused_kernel(
    const float* __restrict__ W_hh, const float* __restrict__ xw,
    const float* __restrict__ h0, float* __restrict__ g_cur,
    float* __restrict__ h_last, unsigned* __restrict__ sync,
    unsigned* __restrict__ henc,
    const float* __restrict__ Qx, const float* __restrict__ patterns,
    const float* __restrict__ bkx, const float* __restrict__ bkg,
    const unsigned short* __restrict__ Vt,
    float* __restrict__ pacc, float* __restrict__ pml, int S) {
  unsigned* cnt  = sync + 64;      // [8] per-xcd registration
  unsigned* dec  = sync + 128;     // decision word (0 = undecided)
  unsigned* wctr = sync + 192;     // flash work counter

  __shared__ int role_s;
  __shared__ float hbuf[528];                       // scan h staging (skewed)
  __shared__ unsigned short stage_u16[16384];       // 32 KB: khi/klo; aliases S_f
  __shared__ unsigned short p_lds[32 * 72];
  __shared__ float mrow_s[32], lrow_s[32], alpha_s[32];
  __shared__ int flag_s;
  __shared__ int unit_s;

  if (threadIdx.x == 0) {
    unsigned xcd = __builtin_amdgcn_s_getreg(6164) & 7u;  // HW_REG_XCC_ID
    unsigned my_idx = __hip_atomic_fetch_add(&cnt[xcd], 1u, __ATOMIC_ACQ_REL,
                                             __HIP_MEMORY_SCOPE_AGENT);
    if (blockIdx.x == 0) {
      int chosen = -1;
      while (chosen < 0) {
        for (int x = 0; x < 8; x++)
          if (__hip_atomic_load(&cnt[x], __ATOMIC_ACQUIRE,
                                __HIP_MEMORY_SCOPE_AGENT) >= (unsigned)SCAN_ROLES) {
            chosen = x; break;
          }
        if (chosen < 0) __builtin_amdgcn_s_sleep(2);
      }
      __hip_atomic_store(dec, 1u + (unsigned)chosen, __ATOMIC_RELEASE,
                         __HIP_MEMORY_SCOPE_AGENT);
    }
    unsigned d;
    while ((d = __hip_atomic_load(dec, __ATOMIC_ACQUIRE,
                                  __HIP_MEMORY_SCOPE_AGENT)) == 0u)
      __builtin_amdgcn_s_sleep(2);
    if (xcd == d - 1u) role_s = (my_idx < (unsigned)SCAN_ROLES) ? (int)my_idx : -2;
    else               role_s = -1;
  }
  __syncthreads();                  // all 8 waves alive here
  const int role = role_s;
  if (role == -2) return;           // elected-XCD non-scan: keep that XCD clean

  if (role >= 0) {
    if (threadIdx.x >= 64) return;  // scan uses wave 0 only
    // ================= scan (round-3 body, verbatim) =================
    const int lane = threadIdx.x;          // 0..63
    const int g    = lane & 3;             // col group: cols [g*128, g*128+128)
    const int row  = role * 16 + (lane >> 2);

    float4 w[32];
    const float4* wsrc = (const float4*)(W_hh + (size_t)row * H_DIM + g * 128);
#pragma unroll
    for (int i = 0; i < 32; i++) w[i] = wsrc[i];
#pragma unroll
    for (int i = 0; i < 32; i++) {
      asm volatile("" : "+v"(w[i].x), "+v"(w[i].y), "+v"(w[i].z), "+v"(w[i].w));
    }

    float xw_next = xw[row];               // xw[0*H + row]

    for (int t = 0; t < T_STEPS; t++) {
      float xwv = xw_next;
      if (t + 1 < T_STEPS)
        xw_next = xw[(size_t)(t + 1) * H_DIM + row];   // prefetch, hides in poll wait

      if (t == 0) {
#pragma unroll
        for (int j = 0; j < 8; j++) {
          int c = 64 * j + lane;
          hbuf[c + 4 * (j >> 1)] = h0[c];
        }
      } else {
        const unsigned* src = henc + (size_t)(t - 1) * H_DIM;
        unsigned u[8];
#pragma unroll
        for (int j = 0; j < 8; j++)
          u[j] = __hip_atomic_load(src + 64 * j + lane, __ATOMIC_RELAXED,
                                   __HIP_MEMORY_SCOPE_AGENT);
        bool again = true;
        while (again) {
          again = false;
#pragma unroll
          for (int j = 0; j < 8; j++)
            if (__builtin_bit_cast(float, u[j]) < 1.0f) {
              again = true;
              u[j] = __hip_atomic_load(src + 64 * j + lane, __ATOMIC_RELAXED,
                                       __HIP_MEMORY_SCOPE_AGENT);
            }
        }
#pragma unroll
        for (int j = 0; j < 8; j++) {
          int c = 64 * j + lane;
          hbuf[c + 4 * (j >> 1)] = __builtin_bit_cast(float, u[j]) - 2.0f;
        }
      }
      asm volatile("s_waitcnt lgkmcnt(0)" ::: "memory");

      const float4* hb = (const float4*)&hbuf[g * 132];
      float a0 = 0.f, a1 = 0.f, a2 = 0.f, a3 = 0.f;
#pragma unroll
      for (int i = 0; i < 8; i++) {
        float4 x0 = hb[4 * i], x1 = hb[4 * i + 1], x2 = hb[4 * i + 2], x3 = hb[4 * i + 3];
        float4 w0 = w[4 * i], w1 = w[4 * i + 1], w2 = w[4 * i + 2], w3 = w[4 * i + 3];
        a0 += x0.x * w0.x + x0.y * w0.y + x0.z * w0.z + x0.w * w0.w;
        a1 += x1.x * w1.x + x1.y * w1.y + x1.z * w1.z + x1.w * w1.w;
        a2 += x2.x * w2.x + x2.y * w2.y + x2.z * w2.z + x2.w * w2.w;
        a3 += x3.x * w3.x + x3.y * w3.y + x3.z * w3.z + x3.w * w3.w;
      }
      float a = (a0 + a1) + (a2 + a3);
      a += __shfl_xor(a, 1, 4);
      a += __shfl_xor(a, 2, 4);

      if (g == 0) {
        float pre = a + xwv;
        float e = __expf(2.f * pre);
        float h = 1.f - 2.f / (e + 1.f);
        __hip_atomic_store(henc + (size_t)t * H_DIM + row,
                           __builtin_bit_cast(unsigned, h + 2.0f),
                           __ATOMIC_RELAXED, __HIP_MEMORY_SCOPE_AGENT);
        g_cur[(size_t)t * H_DIM + row] = h;
        if (t == T_STEPS - 1) h_last[row] = h;
      }
    }
    return;
  }

  // ================= helper: flash work units =================
  const int lane = threadIdx.x & 63;
  const int wid  = threadIdx.x >> 6;    // 0..7
  const int qg   = wid >> 2;            // query group
  const int kw   = wid & 3;             // key sub-block / vd slice
  const int quad = lane >> 4;
  const int l16  = lane & 15;
  const int row2 = threadIdx.x >> 4;    // 0..31
  const int c0   = threadIdx.x & 15;
  const int NU   = 64 * S;              // 2 rets x 32 qtiles x S

  for (;;) {
    if (threadIdx.x == 0)
      unit_s = (int)__hip_atomic_fetch_add(wctr, 1u, __ATOMIC_RELAXED,
                                           __HIP_MEMORY_SCOPE_AGENT);
    __syncthreads();
    const int u = unit_s;
    if (u >= NU) break;

    int ret, qt, sidx;
    if (u < 32 * S) { ret = 1; qt = u & 31; sidx = u >> 5; }          // x-retrieval first
    else { int v = u - 32 * S; qt = v / S; sidx = v - qt * S; ret = 0; } // g: qt ascending
    const int qbase = qt * 32;

    const float* Kp  = patterns + (ret ? 0 : O_DIM);
    const float* bkk = ret ? bkx : bkg;
    const int chunk = M_PAT / S;
    const int kbeg = sidx * chunk, kend = kbeg + chunk;

    // ---- Q fragments: ret=1 from Qx; ret=0 from henc (poll, enc = h+2) ----
    const int qrow = qbase + qg * 16 + l16;
    s16x8 qhi[16], qlo[16];
#pragma unroll
    for (int kst = 0; kst < 16; kst++) {
      float fv[8];
      if (ret) {
        const float4* src = (const float4*)(Qx + (size_t)qrow * 512 + kst * 32 + quad * 8);
        float4 a = src[0], b = src[1];
        fv[0] = a.x; fv[1] = a.y; fv[2] = a.z; fv[3] = a.w;
        fv[4] = b.x; fv[5] = b.y; fv[6] = b.z; fv[7] = b.w;
      } else {
        const unsigned* hs = henc + (size_t)qrow * H_DIM + kst * 32 + quad * 8;
#pragma unroll
        for (int j = 0; j < 8; j++) {
          unsigned uv = __hip_atomic_load(hs + j, __ATOMIC_RELAXED,
                                          __HIP_MEMORY_SCOPE_AGENT);
          while (__builtin_bit_cast(float, uv) < 1.0f) {
            __builtin_amdgcn_s_sleep(8);     // back off: don't flood the LLC
            uv = __hip_atomic_load(hs + j, __ATOMIC_RELAXED,
                                   __HIP_MEMORY_SCOPE_AGENT);
          }
          fv[j] = __builtin_bit_cast(float, uv) - 2.0f;
        }
      }
      s16x8 h, l;
#pragma unroll
      for (int j = 0; j < 8; j++) {
        unsigned short hb, lb; bf_split(fv[j], hb, lb);
        h[j] = (short)hb; l[j] = (short)lb;
      }
      qhi[kst] = h; qlo[kst] = l;
    }

    if (threadIdx.x < 32) { mrow_s[threadIdx.x] = -INFINITY; lrow_s[threadIdx.x] = 0.f; }

    f32x4 o[8];
#pragma unroll
    for (int nb = 0; nb < 8; nb++) o[nb] = (f32x4){0.f, 0.f, 0.f, 0.f};
    float ov[32];
    if (!USE_VT) {
#pragma unroll
      for (int j = 0; j < 32; j++) ov[j] = 0.f;
    }

    for (int k0 = kbeg; k0 < kend; k0 += 64) {
      // ---------------- phase 1: scores ----------------
      f32x4 sc = (f32x4){0.f, 0.f, 0.f, 0.f};
#pragma unroll
      for (int dc = 0; dc < 4; dc++) {
        __syncthreads();                       // stage buffer free (prev reads done)
        if (dc == 0 && threadIdx.x == 0) flag_s = 0;
#pragma unroll
        for (int i = 0; i < 2; i++) {
          int oid = threadIdx.x + 512 * i;     // 1024 octets: key*16 + oct
          int key = oid >> 4, oct = oid & 15;
          const float4* src = (const float4*)(Kp + (size_t)(k0 + key) * 1024 + dc * 128 + oct * 8);
          float4 a = src[0], b = src[1];
          float fv[8] = {a.x, a.y, a.z, a.w, b.x, b.y, b.z, b.w};
          s16x8 hv, lv;
#pragma unroll
          for (int j = 0; j < 8; j++) {
            unsigned short hb, lb; bf_split(fv[j], hb, lb);
            hv[j] = (short)hb; lv[j] = (short)lb;
          }
          int base = (key * 16 + (oct ^ (key & 7))) * 8;
          *(s16x8*)&stage_u16[base] = hv;
          *(s16x8*)&stage_u16[8192 + base] = lv;
        }
        __syncthreads();
#pragma unroll
        for (int ks = 0; ks < 4; ks++) {
          int kst = dc * 4 + ks;
          int key = kw * 16 + l16;
          int oct = ks * 4 + quad;
          int base = (key * 16 + (oct ^ (key & 7))) * 8;
          s16x8 kh = *(const s16x8*)&stage_u16[base];
          s16x8 kl = *(const s16x8*)&stage_u16[8192 + base];
          sc = __builtin_amdgcn_mfma_f32_16x16x32_bf16(qhi[kst], kh, sc, 0, 0, 0);
          sc = __builtin_amdgcn_mfma_f32_16x16x32_bf16(qlo[kst], kh, sc, 0, 0, 0);
          sc = __builtin_amdgcn_mfma_f32_16x16x32_bf16(qhi[kst], kl, sc, 0, 0, 0);
        }
      }
      float bkv = bkk[k0 + kw * 16 + l16];
      __syncthreads();                         // all K reads done; stage aliases S_f now
      float* S_f = (float*)stage_u16;          // [32][68]
#pragma unroll
      for (int r = 0; r < 4; r++)
        S_f[(qg * 16 + quad * 4 + r) * 68 + kw * 16 + l16] = 16.f * sc[r] - bkv;
      __syncthreads();

      // ---------------- phase 2: online softmax ----------------
      float s4[4], p4[4];
#pragma unroll
      for (int c = 0; c < 4; c++) s4[c] = S_f[row2 * 68 + c0 + 16 * c];
      float tmax = fmaxf(fmaxf(s4[0], s4[1]), fmaxf(s4[2], s4[3]));
#pragma unroll
      for (int off = 1; off < 16; off <<= 1) tmax = fmaxf(tmax, __shfl_xor(tmax, off, 16));
      float mold = mrow_s[row2];
      float mnew = fmaxf(mold, tmax);
      float tsum = 0.f;
#pragma unroll
      for (int c = 0; c < 4; c++) { p4[c] = __expf(s4[c] - mnew); tsum += p4[c]; }
#pragma unroll
      for (int off = 1; off < 16; off <<= 1) tsum += __shfl_xor(tsum, off, 16);
#pragma unroll
      for (int c = 0; c < 4; c++) p_lds[row2 * 72 + c0 + 16 * c] = f2bf(p4[c]);
      if (c0 == 0) {
        float al = __expf(mold - mnew);
        alpha_s[row2] = al;
        mrow_s[row2] = mnew;
        lrow_s[row2] = lrow_s[row2] * al + tsum;
        if (tmax > mold - 25.f) flag_s = 1;
      }
      __syncthreads();
      const int doPV = flag_s;

      // ---------------- phase 3: PV ----------------
      if (doPV) {
        if (USE_VT) {
          float alr[4];
#pragma unroll
          for (int r = 0; r < 4; r++) alr[r] = alpha_s[qg * 16 + quad * 4 + r];
#pragma unroll
          for (int nb = 0; nb < 8; nb++) {
            o[nb][0] *= alr[0]; o[nb][1] *= alr[1]; o[nb][2] *= alr[2]; o[nb][3] *= alr[3];
          }
#pragma unroll
          for (int ks2 = 0; ks2 < 2; ks2++) {
            s16x8 pf = *(const s16x8*)&p_lds[(qg * 16 + l16) * 72 + ks2 * 32 + quad * 8];
#pragma unroll
            for (int nb = 0; nb < 8; nb++) {
              int vd = kw * 128 + nb * 16 + l16;
              s16x8 vf = *(const s16x8*)(Vt + (size_t)vd * VT_STR + (k0 + ks2 * 32 + quad * 8));
              o[nb] = __builtin_amdgcn_mfma_f32_16x16x32_bf16(pf, vf, o[nb], 0, 0, 0);
            }
          }
        } else {
          float al = alpha_s[row2];
#pragma unroll
          for (int j = 0; j < 32; j++) ov[j] *= al;
          for (int key = 0; key < 64; key++) {
            float w = bf2f(p_lds[row2 * 72 + key]);
            const float4* vsrc = (const float4*)(patterns + (size_t)(k0 + key) * 1024 + c0 * 32);
#pragma unroll
            for (int j = 0; j < 8; j++) {
              float4 v = vsrc[j];
              ov[4 * j + 0] += w * v.x; ov[4 * j + 1] += w * v.y;
              ov[4 * j + 2] += w * v.z; ov[4 * j + 3] += w * v.w;
            }
          }
        }
      }
    }

    // ---------------- epilogue: unnormalized partials + (m,l) ----------------
    __syncthreads();
    size_t pbase = ((size_t)(ret * S + sidx) * T_STEPS + qbase);
    if (USE_VT) {
#pragma unroll
      for (int nb = 0; nb < 8; nb++)
#pragma unroll
        for (int r = 0; r < 4; r++)
          pacc[(pbase + qg * 16 + quad * 4 + r) * 512 + kw * 128 + nb * 16 + l16] = o[nb][r];
    } else {
#pragma unroll
      for (int j = 0; j < 32; j++)
        pacc[(pbase + row2) * 512 + c0 * 32 + j] = ov[j];
    }
    if (threadIdx.x < 32) {
      pml[(pbase + threadIdx.x) * 2]     = mrow_s[threadIdx.x];
      pml[(pbase + threadIdx.x) * 2 + 1] = lrow_s[threadIdx.x];
    }
    __syncthreads();                 // LDS safe for next unit
  }
}

// ---------------------------------------------------------------------------
// K5: combine key-split partials -> prob_g / prob_x
// ---------------------------------------------------------------------------
__global__ __launch_bounds__(256) void combine_kernel(
    const float* __restrict__ pacc, const float* __restrict__ pml,
    float* __restrict__ out, int S) {
  int b = blockIdx.x;              // ret*1024 + r
  int ret = b >> 10, r = b & 1023;
  float M = -INFINITY;
  for (int s = 0; s < S; s++)
    M = fmaxf(M, pml[((size_t)(ret * S + s) * T_STEPS + r) * 2]);
  float L = 0.f;
  for (int s = 0; s < S; s++) {
    size_t mb = ((size_t)(ret * S + s) * T_STEPS + r) * 2;
    L += pml[mb + 1] * __expf(pml[mb] - M);
  }
  float inv = 1.0f / L;
  for (int cc = threadIdx.x; cc < 512; cc += 256) {
    float acc = 0.f;
    for (int s = 0; s < S; s++) {
      size_t mb = ((size_t)(ret * S + s) * T_STEPS + r) * 2;
      float sc = __expf(pml[mb] - M);
      acc += sc * pacc[((size_t)(ret * S + s) * T_STEPS + r) * 512 + cc];
    }
    out[(size_t)ret * (T_STEPS * O_DIM) + (size_t)r * 512 + cc] = acc * inv;
  }
}

// ---------------------------------------------------------------------------
extern "C" void kernel_launch(void* const* d_in, const int* in_sizes, int n_in,
                              void* d_out, int out_size, void* d_ws, size_t ws_size,
                              hipStream_t stream) {
  const float* inp      = (const float*)d_in[0];
  const float* x_obs    = (const float*)d_in[1];
  const float* patterns = (const float*)d_in[2];
  const float* h0       = (const float*)d_in[3];
  const float* W_ih     = (const float*)d_in[4];
  const float* W_hh     = (const float*)d_in[5];
  const float* b_ih     = (const float*)d_in[6];
  const float* b_hh     = (const float*)d_in[7];

  float* out    = (float*)d_out;
  float* g_cur  = out + 1048576;               // 1024*512
  float* h_last = out + 1572864;               // 512

  char* wsb = (char*)d_ws;
  size_t off = 0;
  auto alloc = [&](size_t bytes) -> char* {
    char* p = wsb + off; off += (bytes + 255) & ~(size_t)255; return p;
  };
  unsigned* sync = (unsigned*)alloc(8192);
  unsigned* henc = (unsigned*)alloc((size_t)T_STEPS * H_DIM * 4);   // 2 MB
  float* xw  = (float*)alloc((size_t)T_STEPS * H_DIM * 4);
  float* bkx = (float*)alloc((size_t)M_PAT * 4);
  float* bkg = (float*)alloc((size_t)M_PAT * 4);
  size_t base = off;

  const size_t vt_bytes = (size_t)512 * VT_STR * 2;
  auto pml_bytes  = [](int S) { return (size_t)2 * S * T_STEPS * 2 * 4; };
  auto pacc_bytes = [](int S) { return (size_t)2 * S * T_STEPS * 512 * 4; };

  int S = 4; bool use_vt = false;
  if      (base + pml_bytes(16) + pacc_bytes(16) + vt_bytes + 1024 <= ws_size) { S = 16; use_vt = true; }
  else if (base + pml_bytes(8)  + pacc_bytes(8)  + vt_bytes + 1024 <= ws_size) { S = 8;  use_vt = true; }
  else if (base + pml_bytes(4)  + pacc_bytes(4)  + vt_bytes + 1024 <= ws_size) { S = 4;  use_vt = true; }
  else if (base + pml_bytes(2)  + pacc_bytes(2)  + vt_bytes + 1024 <= ws_size) { S = 2;  use_vt = true; }
  else if (base + pml_bytes(4)  + pacc_bytes(4)  + 1024 <= ws_size)            { S = 4;  use_vt = false; }
  else if (base + pml_bytes(2)  + pacc_bytes(2)  + 1024 <= ws_size)            { S = 2;  use_vt = false; }
  else { S = 1; use_vt = false; }

  float* pml  = (float*)alloc(pml_bytes(S));
  float* pacc = (float*)alloc(pacc_bytes(S));
  unsigned short* Vt = use_vt ? (unsigned short*)alloc(vt_bytes) : (unsigned short*)nullptr;

  hipMemsetAsync(sync, 0, 8192, stream);
  hipMemsetAsync(henc, 0, (size_t)T_STEPS * H_DIM * 4, stream);
  xw_kernel<<<T_STEPS, 256, 0, stream>>>(inp, W_ih, b_ih, b_hh, xw);
  norms_kernel<<<M_PAT / 4, 256, 0, stream>>>(patterns, bkx, bkg);
  if (use_vt) {
    vt_kernel<<<dim3(512, 8), 256, 0, stream>>>(patterns, Vt);
    fused_kernel<true><<<1024, 512, 0, stream>>>(W_hh, xw, h0, g_cur, h_last, sync, henc,
                                                 x_obs, patterns, bkx, bkg, Vt, pacc, pml, S);
  } else {
    fused_kernel<false><<<1024, 512, 0, stream>>>(W_hh, xw, h0, g_cur, h_last, sync, henc,
                                                  x_obs, patterns, bkx, bkg, nullptr, pacc, pml, S);
  }
  combine_kernel<<<2 * T_STEPS, 256, 0, stream>>>(pacc, pml, out, S);
}